// Round 12
// baseline (223.836 us; speedup 1.0000x reference)
//
#include <hip/hip_runtime.h>
#include <math.h>

#define EMB_K   768
#define NH      96
#define SEQLEN  2048
#define NBATCH  16
#define MROWS   (NBATCH * SEQLEN)   // 32768

typedef __bf16 v8bf __attribute__((ext_vector_type(8)));
typedef float  v4f  __attribute__((ext_vector_type(4)));

// score scale folded into Q at qkv epilogue: (1/sqrt(96)) * log2(e)
#define QSCALE (0.10206207261596575f * 1.4426950408889634f)

#if __has_builtin(__builtin_amdgcn_global_load_lds)
#define ASYNC_LDS 1
#else
#define ASYNC_LDS 0
#endif

// ---------------------------------------------------------------------------
// Pack Wq/Wk/Wv (fp32 [768][96]) into bf16 B-fragment order. (unchanged)
// ---------------------------------------------------------------------------
__global__ __launch_bounds__(256) void pack_w(
    const float* __restrict__ Wq,
    const float* __restrict__ Wk,
    const float* __restrict__ Wv,
    __bf16* __restrict__ Wp)
{
    int t = blockIdx.x * 256 + threadIdx.x;
    if (t >= 3 * 24 * 6 * 64) return;
    int l  = t & 63;
    int fj = (t >> 6) % 6;
    int s  = ((t >> 6) / 6) % 24;
    int w  = (t >> 6) / (6 * 24);
    const float* W = (w == 0) ? Wq : ((w == 1) ? Wk : Wv);
    int n     = fj * 16 + (l & 15);
    int kbase = s * 32 + (l >> 4) * 8;
    __bf16 o[8];
    #pragma unroll
    for (int e = 0; e < 8; ++e)
        o[e] = (__bf16)W[(size_t)(kbase + e) * NH + n];
    *(v8bf*)(Wp + (size_t)t * 8) = *(v8bf*)o;
}

__device__ inline v8bf cvt8(const float4& a, const float4& b)
{
    v8bf r;
    r[0] = (__bf16)a.x; r[1] = (__bf16)a.y; r[2] = (__bf16)a.z; r[3] = (__bf16)a.w;
    r[4] = (__bf16)b.x; r[5] = (__bf16)b.y; r[6] = (__bf16)b.z; r[7] = (__bf16)b.w;
    return r;
}

// ---------------------------------------------------------------------------
// Fused QKV — r11 structure (VGPR-staged B + ds_write, x prefetched 2 deep
// across barriers), with the ROUND-12 FIX: __launch_bounds__(256, 2).
// r11's (256,3) capped combined VGPR/AGPR at ~170; acc(72)+btmp(20)+xreg(16)
// + addressing overflowed -> compiler spilled the prefetch temps to scratch
// (WRITE_SIZE 18.4->45 MB, VALUBusy 19->6%). Grid is 512 = 2 blocks/CU max,
// so the ,3 bound bought nothing. (256,2) caps at 256 VGPRs: no spill, and
// the intended pipeline finally runs with live registers.
// ---------------------------------------------------------------------------
__global__ __launch_bounds__(256, 2) void qkv_fused(
    const float* __restrict__ x,
    const __bf16* __restrict__ Wp,
    __bf16* __restrict__ qk,
    __bf16* __restrict__ vt)
{
    __shared__ __bf16 Bs[2][18][512];   // 36.9 KB, double-buffered B frags
    __shared__ __bf16 VsT[96][72];      // 13.8 KB, V transpose bounce

    const int wave = threadIdx.x >> 6;
    const int lane = threadIdx.x & 63;
    const int mlow = lane & 15;
    const int kq   = lane >> 4;
    const int m0   = blockIdx.x * 64;
    const int r0   = m0 + wave * 16;

    const float* xr = x + (size_t)(r0 + mlow) * EMB_K + kq * 8;

    // frags owned by this wave: f = wave + 4*i  (waves 0,1: 5 frags; 2,3: 4)
    const int nf = (wave < 2) ? 5 : 4;

    v4f acc[3][6];
    #pragma unroll
    for (int w = 0; w < 3; ++w)
        #pragma unroll
        for (int j = 0; j < 6; ++j)
            acc[w][j] = (v4f)0.0f;

    // prologue: B(0) -> LDS, x(0), x(1) -> regs
    v8bf btmp[5];
    #pragma unroll
    for (int i = 0; i < 5; ++i)
        if (i < nf) {
            const int f = wave + 4 * i;
            btmp[i] = *(const v8bf*)(Wp + ((size_t)((f / 6) * 24) * 6 + (f % 6)) * 512
                                        + (size_t)lane * 8);
        }
    float4 xreg[2][2];
    xreg[0][0] = *(const float4*)(xr);
    xreg[0][1] = *(const float4*)(xr + 4);
    xreg[1][0] = *(const float4*)(xr + 32);
    xreg[1][1] = *(const float4*)(xr + 36);
    #pragma unroll
    for (int i = 0; i < 5; ++i)
        if (i < nf)
            *(v8bf*)&Bs[0][wave + 4 * i][(size_t)lane * 8] = btmp[i];
    __syncthreads();

    for (int s = 0; s < 24; ++s) {
        const int cur = s & 1;

        // consume x(s) (frees xreg[cur] for the s+2 prefetch)
        v8bf a = cvt8(xreg[cur][0], xreg[cur][1]);

        // issue B(s+1) loads FIRST (older in vmcnt FIFO)...
        if (s < 23) {
            #pragma unroll
            for (int i = 0; i < 5; ++i)
                if (i < nf) {
                    const int f = wave + 4 * i;
                    btmp[i] = *(const v8bf*)(Wp + ((size_t)((f / 6) * 24 + (s + 1)) * 6
                                                   + (f % 6)) * 512 + (size_t)lane * 8);
                }
        }
        // ...then x(s+2) (newer: stays outstanding when B temps are waited on)
        if (s < 22) {
            xreg[cur][0] = *(const float4*)(xr + (s + 2) * 32);
            xreg[cur][1] = *(const float4*)(xr + (s + 2) * 32 + 4);
        }

        // compute on Bs[cur] (covers part of the B-load latency)
        #pragma unroll
        for (int w = 0; w < 3; ++w)
            #pragma unroll
            for (int j = 0; j < 6; ++j) {
                v8bf bf = *(const v8bf*)&Bs[cur][w * 6 + j][(size_t)lane * 8];
                acc[w][j] = __builtin_amdgcn_mfma_f32_16x16x32_bf16(a, bf, acc[w][j], 0, 0, 0);
            }

        // stage B(s+1) into the other buffer (waits vmcnt only for B temps)
        if (s < 23) {
            #pragma unroll
            for (int i = 0; i < 5; ++i)
                if (i < nf)
                    *(v8bf*)&Bs[cur ^ 1][wave + 4 * i][(size_t)lane * 8] = btmp[i];
        }
        __syncthreads();   // lgkm drain only — x prefetch survives
    }

    // Q, K epilogue (Q pre-scaled by QSCALE)
    #pragma unroll
    for (int w = 0; w < 2; ++w) {
        __bf16* op = qk + (size_t)w * MROWS * NH;
        const float sc = (w == 0) ? QSCALE : 1.0f;
        #pragma unroll
        for (int j = 0; j < 6; ++j)
            #pragma unroll
            for (int r = 0; r < 4; ++r)
                op[(size_t)(r0 + kq * 4 + r) * NH + j * 16 + mlow] =
                    (__bf16)(acc[w][j][r] * sc);
    }
    // V -> LDS transposed, then coalesced store to vt[96][32768]
    #pragma unroll
    for (int j = 0; j < 6; ++j)
        #pragma unroll
        for (int r = 0; r < 4; ++r)
            VsT[j * 16 + mlow][wave * 16 + kq * 4 + r] = (__bf16)acc[2][j][r];
    __syncthreads();
    #pragma unroll
    for (int it = 0; it < 3; ++it) {
        int idx = it * 256 + threadIdx.x;
        int c = idx >> 3, g = idx & 7;
        *(v8bf*)(vt + (size_t)c * MROWS + m0 + g * 8) = *(const v8bf*)&VsT[c][g * 8];
    }
}

// ---------------------------------------------------------------------------
// MFMA causal flash attention — block-cooperative K/V staging.
// (byte-identical to round 10 — frozen for attribution)
// ---------------------------------------------------------------------------
__device__ const unsigned char JTAB[30] = {
    20, 24, 28, 32, 36, 40, 44, 45, 48, 49, 52, 53, 56, 57, 60, 61,
    0, 4, 8, 12, 16, 25, 29, 33, 37, 41, 50, 54, 58, 62
};

__global__ __launch_bounds__(256, 2) void attn_mfma(
    const __bf16* __restrict__ qk,
    const __bf16* __restrict__ vt,
    float* __restrict__ out,
    __bf16* __restrict__ Opart,
    float* __restrict__ ml)
{
    __shared__ __bf16 Kf[2][12][512];
    __shared__ __bf16 Vf[2][12][512];
    __shared__ __bf16 Ps[4][16][72];

    const int bid = blockIdx.x;
    const int b   = bid & 15;
    const int j   = bid >> 4;
    const int enc = JTAB[j];
    const int qt  = enc >> 2;
    const int c0  = enc & 3;
    const int ntiles = 2 * qt + 2;
    const int t0  = c0 * 12;
    const int t1  = (t0 + 12 < ntiles) ? (t0 + 12) : ntiles;
    const int nch = (ntiles + 11) / 12;

    const int wave = threadIdx.x >> 6;
    const int lane = threadIdx.x & 63;
    const int mlow = lane & 15;
    const int kq   = lane >> 4;
    const int qw0  = qt * 128 + wave * 32;

    const __bf16* qp  = qk + (size_t)b * SEQLEN * NH;
    const __bf16* kp  = qk + (size_t)MROWS * NH + (size_t)b * SEQLEN * NH;
    const __bf16* vtp = vt + (size_t)b * SEQLEN;

    v8bf qa[2][3];
    #pragma unroll
    for (int g2 = 0; g2 < 2; ++g2)
        #pragma unroll
        for (int s = 0; s < 3; ++s)
            qa[g2][s] = *(const v8bf*)(qp + (size_t)(qw0 + g2 * 16 + mlow) * NH
                                          + s * 32 + kq * 8);

    v4f lsum[2];
    v4f O[2][6];
    #pragma unroll
    for (int g2 = 0; g2 < 2; ++g2) {
        lsum[g2] = (v4f)0.0f;
        #pragma unroll
        for (int jj = 0; jj < 6; ++jj) O[g2][jj] = (v4f)0.0f;
    }

    auto stage = [&](int t, int buf) {
        const int k0 = t * 64;
        #pragma unroll
        for (int i = 0; i < 6; ++i) {
            const int f = wave * 6 + i;
            const __bf16* src;
            __bf16* dst;
            if (f < 12) {
                const int t4 = f / 3, s = f - t4 * 3;
                src = kp + (size_t)(k0 + t4 * 16 + mlow) * NH + s * 32 + kq * 8;
                dst = &Kf[buf][f][0];
            } else {
                const int fv = f - 12;
                const int jj = fv >> 1, h = fv & 1;
                src = vtp + (size_t)(jj * 16 + mlow) * MROWS + k0 + h * 32 + kq * 8;
                dst = &Vf[buf][fv][0];
            }
#if ASYNC_LDS
            __builtin_amdgcn_global_load_lds(
                (const __attribute__((address_space(1))) void*)src,
                (__attribute__((address_space(3))) void*)dst,
                16, 0, 0);
#else
            *(v8bf*)(dst + (size_t)lane * 8) = *(const v8bf*)src;
#endif
        }
    };

    stage(t0, 0);
    __syncthreads();

    for (int t = t0; t < t1; ++t) {
        const int buf = (t - t0) & 1;
        if (t + 1 < t1) stage(t + 1, buf ^ 1);
        const int k0 = t * 64;

        if (k0 <= qw0 + 31) {
            const bool msk = (k0 + 63 > qw0);
            #pragma unroll
            for (int g2 = 0; g2 < 2; ++g2) {
                float s2[4][4];
                #pragma unroll
                for (int t4 = 0; t4 < 4; ++t4) {
                    v4f sa = (v4f)0.0f;
                    #pragma unroll
                    for (int s = 0; s < 3; ++s) {
                        v8bf kb = *(const v8bf*)&Kf[buf][t4 * 3 + s][(size_t)lane * 8];
                        sa = __builtin_amdgcn_mfma_f32_16x16x32_bf16(qa[g2][s], kb, sa, 0, 0, 0);
                    }
                    #pragma unroll
                    for (int r = 0; r < 4; ++r) s2[t4][r] = sa[r];
                }
                if (msk) {
                    #pragma unroll
                    for (int t4 = 0; t4 < 4; ++t4)
                        #pragma unroll
                        for (int r = 0; r < 4; ++r)
                            if (k0 + t4 * 16 + mlow > qw0 + g2 * 16 + kq * 4 + r)
                                s2[t4][r] = -1e20f;
                }

                v4f pvv[4];
                #pragma unroll
                for (int t4 = 0; t4 < 4; ++t4)
                    #pragma unroll
                    for (int r = 0; r < 4; ++r)
                        pvv[t4][r] = exp2f(s2[t4][r]);
                lsum[g2] += (pvv[0] + pvv[1]) + (pvv[2] + pvv[3]);

                #pragma unroll
                for (int t4 = 0; t4 < 4; ++t4)
                    #pragma unroll
                    for (int r = 0; r < 4; ++r)
                        Ps[wave][kq * 4 + r][t4 * 16 + mlow] = (__bf16)pvv[t4][r];

                v8bf pa0 = *(const v8bf*)&Ps[wave][mlow][kq * 8];
                v8bf pa1 = *(const v8bf*)&Ps[wave][mlow][32 + kq * 8];

                #pragma unroll
                for (int jj = 0; jj < 6; ++jj) {
                    v8bf vb0 = *(const v8bf*)&Vf[buf][jj * 2][(size_t)lane * 8];
                    v8bf vb1 = *(const v8bf*)&Vf[buf][jj * 2 + 1][(size_t)lane * 8];
                    O[g2][jj] = __builtin_amdgcn_mfma_f32_16x16x32_bf16(pa0, vb0, O[g2][jj], 0, 0, 0);
                    O[g2][jj] = __builtin_amdgcn_mfma_f32_16x16x32_bf16(pa1, vb1, O[g2][jj], 0, 0, 0);
                }
            }
        }
        __syncthreads();
    }

    #pragma unroll
    for (int off = 1; off < 16; off <<= 1)
        #pragma unroll
        for (int g2 = 0; g2 < 2; ++g2)
            #pragma unroll
            for (int r = 0; r < 4; ++r)
                lsum[g2][r] += __shfl_xor(lsum[g2][r], off);

    if (nch == 1) {
        #pragma unroll
        for (int g2 = 0; g2 < 2; ++g2)
            #pragma unroll
            for (int r = 0; r < 4; ++r) {
                float inv = 1.0f / lsum[g2][r];
                float* orow = out + ((size_t)b * SEQLEN + qw0 + g2 * 16 + kq * 4 + r) * NH;
                #pragma unroll
                for (int jj = 0; jj < 6; ++jj)
                    orow[jj * 16 + mlow] = O[g2][jj][r] * inv;
            }
    } else {
        const int e = (b * 10 + (qt - 6)) * 3 + c0;
        __bf16* Pp = Opart + (size_t)e * 12288;
        #pragma unroll
        for (int g2 = 0; g2 < 2; ++g2)
            #pragma unroll
            for (int r = 0; r < 4; ++r) {
                const int row = wave * 32 + g2 * 16 + kq * 4 + r;
                float inv = 1.0f / lsum[g2][r];
                #pragma unroll
                for (int jj = 0; jj < 6; ++jj)
                    Pp[row * 96 + jj * 16 + mlow] = (__bf16)(O[g2][jj][r] * inv);
                if (mlow == 0) {
                    ml[(size_t)e * 256 + row * 2]     = 0.0f;
                    ml[(size_t)e * 256 + row * 2 + 1] = lsum[g2][r];
                }
            }
    }
}

// ---------------------------------------------------------------------------
// Merge 2..3 partials per (b, qt>=6). (unchanged)
// ---------------------------------------------------------------------------
__global__ __launch_bounds__(256) void attn_combine(
    const __bf16* __restrict__ Opart,
    const float* __restrict__ ml,
    float* __restrict__ out)
{
    __shared__ float wsh[3][128];
    const int b   = blockIdx.x & 15;
    const int qr  = blockIdx.x >> 4;
    const int qt  = 6 + qr;
    const int nch = (qt >= 12) ? 3 : 2;
    const int e0  = (b * 10 + qr) * 3;
    const int tid = threadIdx.x;

    if (tid < 128) {
        float m[3], l[3];
        float M = -INFINITY;
        #pragma unroll
        for (int c = 0; c < 3; ++c) {
            if (c < nch) {
                m[c] = ml[(size_t)(e0 + c) * 256 + tid * 2];
                l[c] = ml[(size_t)(e0 + c) * 256 + tid * 2 + 1];
            } else { m[c] = -INFINITY; l[c] = 0.0f; }
            M = fmaxf(M, m[c]);
        }
        float a[3], s = 0.0f;
        #pragma unroll
        for (int c = 0; c < 3; ++c) { a[c] = exp2f(m[c] - M) * l[c]; s += a[c]; }
        float inv = 1.0f / s;
        #pragma unroll
        for (int c = 0; c < 3; ++c) wsh[c][tid] = a[c] * inv;
    }
    __syncthreads();

    float* op = out + ((size_t)b * SEQLEN + (size_t)qt * 128) * NH;
    #pragma unroll
    for (int it = 0; it < 6; ++it) {
        int idx = it * 256 + tid;
        int row = idx / 12;
        int off = idx * 8;
        float acc[8];
        #pragma unroll
        for (int k = 0; k < 8; ++k) acc[k] = 0.0f;
        #pragma unroll
        for (int c = 0; c < 3; ++c) {
            if (c < nch) {
                v8bf p = *(const v8bf*)(Opart + (size_t)(e0 + c) * 12288 + off);
                float w = wsh[c][row];
                #pragma unroll
                for (int k = 0; k < 8; ++k) acc[k] += w * (float)p[k];
            }
        }
        *(float4*)(op + off)     = make_float4(acc[0], acc[1], acc[2], acc[3]);
        *(float4*)(op + off + 4) = make_float4(acc[4], acc[5], acc[6], acc[7]);
    }
}

// ---------------------------------------------------------------------------
extern "C" void kernel_launch(void* const* d_in, const int* in_sizes, int n_in,
                              void* d_out, int out_size, void* d_ws, size_t ws_size,
                              hipStream_t stream)
{
    (void)in_sizes; (void)n_in; (void)out_size; (void)ws_size;
    const float* x  = (const float*)d_in[0];
    const float* Wq = (const float*)d_in[1];
    const float* Wk = (const float*)d_in[2];
    const float* Wv = (const float*)d_in[3];
    float* out = (float*)d_out;

    __bf16* qk    = (__bf16*)d_ws;                          // 12.58 MB (Q,K)
    __bf16* vt    = qk + (size_t)2 * MROWS * NH;            //  6.29 MB (V^T)
    __bf16* Wp    = vt + (size_t)NH * MROWS;                //  0.44 MB
    __bf16* Opart = Wp + (size_t)3 * 24 * 6 * 512;          // 11.80 MB (bf16)
    float*  ml    = (float*)(Opart + (size_t)480 * 12288);  //  0.49 MB

    pack_w<<<(3 * 24 * 6 * 64 + 255) / 256, 256, 0, stream>>>(Wq, Wk, Wv, Wp);
    qkv_fused<<<MROWS / 64, 256, 0, stream>>>(x, Wp, qk, vt);
    attn_mfma<<<dim3(480), 256, 0, stream>>>(qk, vt, out, Opart, ml);
    attn_combine<<<dim3(160), 256, 0, stream>>>(Opart, ml, out);
}

// Round 13
// 206.742 us; speedup vs baseline: 1.0827x; 1.0827x over previous
//
#include <hip/hip_runtime.h>
#include <math.h>

#define EMB_K   768
#define NH      96
#define SEQLEN  2048
#define NBATCH  16
#define MROWS   (NBATCH * SEQLEN)   // 32768

typedef __bf16 v8bf __attribute__((ext_vector_type(8)));
typedef float  v4f  __attribute__((ext_vector_type(4)));

// score scale folded into Q at qkv epilogue: (1/sqrt(96)) * log2(e)
#define QSCALE (0.10206207261596575f * 1.4426950408889634f)

#if __has_builtin(__builtin_amdgcn_global_load_lds)
#define ASYNC_LDS 1
#else
#define ASYNC_LDS 0
#endif

// ---------------------------------------------------------------------------
// Pack Wq/Wk/Wv (fp32 [768][96]) into bf16 B-fragment order. (unchanged)
// ---------------------------------------------------------------------------
__global__ __launch_bounds__(256) void pack_w(
    const float* __restrict__ Wq,
    const float* __restrict__ Wk,
    const float* __restrict__ Wv,
    __bf16* __restrict__ Wp)
{
    int t = blockIdx.x * 256 + threadIdx.x;
    if (t >= 3 * 24 * 6 * 64) return;
    int l  = t & 63;
    int fj = (t >> 6) % 6;
    int s  = ((t >> 6) / 6) % 24;
    int w  = (t >> 6) / (6 * 24);
    const float* W = (w == 0) ? Wq : ((w == 1) ? Wk : Wv);
    int n     = fj * 16 + (l & 15);
    int kbase = s * 32 + (l >> 4) * 8;
    __bf16 o[8];
    #pragma unroll
    for (int e = 0; e < 8; ++e)
        o[e] = (__bf16)W[(size_t)(kbase + e) * NH + n];
    *(v8bf*)(Wp + (size_t)t * 8) = *(v8bf*)o;
}

__device__ inline v8bf cvt8(const float4& a, const float4& b)
{
    v8bf r;
    r[0] = (__bf16)a.x; r[1] = (__bf16)a.y; r[2] = (__bf16)a.z; r[3] = (__bf16)a.w;
    r[4] = (__bf16)b.x; r[5] = (__bf16)b.y; r[6] = (__bf16)b.z; r[7] = (__bf16)b.w;
    return r;
}

// ---------------------------------------------------------------------------
// Fused QKV — ROUND 13: the r11 pipeline with the REAL bug fixed.
// r11/r12's loop indexed xreg[cur] with cur = s&1 (runtime) -> dynamic index
// into a register array -> compiler demoted the x-prefetch regs to SCRATCH
// (WRITE_SIZE 18.4->45 MB, VALUBusy 6%, VGPR 76). (Same failure class as r4;
// r5's "fixed" version only worked because a 4-iter loop could fully unroll.)
// Fix: manual 2x unroll with NAMED register pairs (x0a/x0b even slices,
// x1a/x1b odd) — no dynamic register indexing anywhere. Bs[buf] indices are
// now literals too. Pipeline semantics unchanged: B(s+1) via VGPR temps +
// ds_write_b128 (barrier drains lgkm + older B vmcnt only), x prefetched
// 2 slices deep and SURVIVING barriers.
// ---------------------------------------------------------------------------
__global__ __launch_bounds__(256, 2) void qkv_fused(
    const float* __restrict__ x,
    const __bf16* __restrict__ Wp,
    __bf16* __restrict__ qk,
    __bf16* __restrict__ vt)
{
    __shared__ __bf16 Bs[2][18][512];   // 36.9 KB, double-buffered B frags
    __shared__ __bf16 VsT[96][72];      // 13.8 KB, V transpose bounce

    const int wave = threadIdx.x >> 6;
    const int lane = threadIdx.x & 63;
    const int mlow = lane & 15;
    const int kq   = lane >> 4;
    const int m0   = blockIdx.x * 64;
    const int r0   = m0 + wave * 16;

    const float* xr = x + (size_t)(r0 + mlow) * EMB_K + kq * 8;

    // frags owned by this wave: f = wave + 4*i  (waves 0,1: 5 frags; 2,3: 4)
    const int nf = (wave < 2) ? 5 : 4;

    v4f acc[3][6];
    #pragma unroll
    for (int w = 0; w < 3; ++w)
        #pragma unroll
        for (int j = 0; j < 6; ++j)
            acc[w][j] = (v4f)0.0f;

    // prologue: B(0) -> LDS, x(0), x(1) -> named regs
    v8bf btmp[5];
    #pragma unroll
    for (int i = 0; i < 5; ++i)
        if (i < nf) {
            const int f = wave + 4 * i;
            btmp[i] = *(const v8bf*)(Wp + ((size_t)((f / 6) * 24) * 6 + (f % 6)) * 512
                                        + (size_t)lane * 8);
        }
    float4 x0a = *(const float4*)(xr);
    float4 x0b = *(const float4*)(xr + 4);
    float4 x1a = *(const float4*)(xr + 32);
    float4 x1b = *(const float4*)(xr + 36);
    #pragma unroll
    for (int i = 0; i < 5; ++i)
        if (i < nf)
            *(v8bf*)&Bs[0][wave + 4 * i][(size_t)lane * 8] = btmp[i];
    __syncthreads();

    for (int sp = 0; sp < 12; ++sp) {
        // ---- even slice s0 = 2*sp, consumes x0*, computes on Bs[0] ----
        {
            const int s0 = 2 * sp;
            v8bf a = cvt8(x0a, x0b);
            // B(s0+1) loads first (older in vmcnt FIFO)
            #pragma unroll
            for (int i = 0; i < 5; ++i)
                if (i < nf) {
                    const int f = wave + 4 * i;
                    btmp[i] = *(const v8bf*)(Wp + ((size_t)((f / 6) * 24 + (s0 + 1)) * 6
                                                   + (f % 6)) * 512 + (size_t)lane * 8);
                }
            // x(s0+2) second (newer: stays in flight across the B wait)
            if (s0 < 22) {
                x0a = *(const float4*)(xr + (s0 + 2) * 32);
                x0b = *(const float4*)(xr + (s0 + 2) * 32 + 4);
            }
            #pragma unroll
            for (int w = 0; w < 3; ++w)
                #pragma unroll
                for (int j = 0; j < 6; ++j) {
                    v8bf bf = *(const v8bf*)&Bs[0][w * 6 + j][(size_t)lane * 8];
                    acc[w][j] = __builtin_amdgcn_mfma_f32_16x16x32_bf16(a, bf, acc[w][j], 0, 0, 0);
                }
            #pragma unroll
            for (int i = 0; i < 5; ++i)
                if (i < nf)
                    *(v8bf*)&Bs[1][wave + 4 * i][(size_t)lane * 8] = btmp[i];
            __syncthreads();
        }
        // ---- odd slice s1 = 2*sp+1, consumes x1*, computes on Bs[1] ----
        {
            const int s1 = 2 * sp + 1;
            v8bf a = cvt8(x1a, x1b);
            if (s1 < 23) {
                #pragma unroll
                for (int i = 0; i < 5; ++i)
                    if (i < nf) {
                        const int f = wave + 4 * i;
                        btmp[i] = *(const v8bf*)(Wp + ((size_t)((f / 6) * 24 + (s1 + 1)) * 6
                                                       + (f % 6)) * 512 + (size_t)lane * 8);
                    }
            }
            if (s1 < 22) {
                x1a = *(const float4*)(xr + (s1 + 2) * 32);
                x1b = *(const float4*)(xr + (s1 + 2) * 32 + 4);
            }
            #pragma unroll
            for (int w = 0; w < 3; ++w)
                #pragma unroll
                for (int j = 0; j < 6; ++j) {
                    v8bf bf = *(const v8bf*)&Bs[1][w * 6 + j][(size_t)lane * 8];
                    acc[w][j] = __builtin_amdgcn_mfma_f32_16x16x32_bf16(a, bf, acc[w][j], 0, 0, 0);
                }
            if (s1 < 23) {
                #pragma unroll
                for (int i = 0; i < 5; ++i)
                    if (i < nf)
                        *(v8bf*)&Bs[0][wave + 4 * i][(size_t)lane * 8] = btmp[i];
            }
            __syncthreads();
        }
    }

    // Q, K epilogue (Q pre-scaled by QSCALE)
    #pragma unroll
    for (int w = 0; w < 2; ++w) {
        __bf16* op = qk + (size_t)w * MROWS * NH;
        const float sc = (w == 0) ? QSCALE : 1.0f;
        #pragma unroll
        for (int j = 0; j < 6; ++j)
            #pragma unroll
            for (int r = 0; r < 4; ++r)
                op[(size_t)(r0 + kq * 4 + r) * NH + j * 16 + mlow] =
                    (__bf16)(acc[w][j][r] * sc);
    }
    // V -> LDS transposed, then coalesced store to vt[96][32768]
    #pragma unroll
    for (int j = 0; j < 6; ++j)
        #pragma unroll
        for (int r = 0; r < 4; ++r)
            VsT[j * 16 + mlow][wave * 16 + kq * 4 + r] = (__bf16)acc[2][j][r];
    __syncthreads();
    #pragma unroll
    for (int it = 0; it < 3; ++it) {
        int idx = it * 256 + threadIdx.x;
        int c = idx >> 3, g = idx & 7;
        *(v8bf*)(vt + (size_t)c * MROWS + m0 + g * 8) = *(const v8bf*)&VsT[c][g * 8];
    }
}

// ---------------------------------------------------------------------------
// MFMA causal flash attention — block-cooperative K/V staging.
// (byte-identical to round 10 — frozen for attribution)
// ---------------------------------------------------------------------------
__device__ const unsigned char JTAB[30] = {
    20, 24, 28, 32, 36, 40, 44, 45, 48, 49, 52, 53, 56, 57, 60, 61,
    0, 4, 8, 12, 16, 25, 29, 33, 37, 41, 50, 54, 58, 62
};

__global__ __launch_bounds__(256, 2) void attn_mfma(
    const __bf16* __restrict__ qk,
    const __bf16* __restrict__ vt,
    float* __restrict__ out,
    __bf16* __restrict__ Opart,
    float* __restrict__ ml)
{
    __shared__ __bf16 Kf[2][12][512];
    __shared__ __bf16 Vf[2][12][512];
    __shared__ __bf16 Ps[4][16][72];

    const int bid = blockIdx.x;
    const int b   = bid & 15;
    const int j   = bid >> 4;
    const int enc = JTAB[j];
    const int qt  = enc >> 2;
    const int c0  = enc & 3;
    const int ntiles = 2 * qt + 2;
    const int t0  = c0 * 12;
    const int t1  = (t0 + 12 < ntiles) ? (t0 + 12) : ntiles;
    const int nch = (ntiles + 11) / 12;

    const int wave = threadIdx.x >> 6;
    const int lane = threadIdx.x & 63;
    const int mlow = lane & 15;
    const int kq   = lane >> 4;
    const int qw0  = qt * 128 + wave * 32;

    const __bf16* qp  = qk + (size_t)b * SEQLEN * NH;
    const __bf16* kp  = qk + (size_t)MROWS * NH + (size_t)b * SEQLEN * NH;
    const __bf16* vtp = vt + (size_t)b * SEQLEN;

    v8bf qa[2][3];
    #pragma unroll
    for (int g2 = 0; g2 < 2; ++g2)
        #pragma unroll
        for (int s = 0; s < 3; ++s)
            qa[g2][s] = *(const v8bf*)(qp + (size_t)(qw0 + g2 * 16 + mlow) * NH
                                          + s * 32 + kq * 8);

    v4f lsum[2];
    v4f O[2][6];
    #pragma unroll
    for (int g2 = 0; g2 < 2; ++g2) {
        lsum[g2] = (v4f)0.0f;
        #pragma unroll
        for (int jj = 0; jj < 6; ++jj) O[g2][jj] = (v4f)0.0f;
    }

    auto stage = [&](int t, int buf) {
        const int k0 = t * 64;
        #pragma unroll
        for (int i = 0; i < 6; ++i) {
            const int f = wave * 6 + i;
            const __bf16* src;
            __bf16* dst;
            if (f < 12) {
                const int t4 = f / 3, s = f - t4 * 3;
                src = kp + (size_t)(k0 + t4 * 16 + mlow) * NH + s * 32 + kq * 8;
                dst = &Kf[buf][f][0];
            } else {
                const int fv = f - 12;
                const int jj = fv >> 1, h = fv & 1;
                src = vtp + (size_t)(jj * 16 + mlow) * MROWS + k0 + h * 32 + kq * 8;
                dst = &Vf[buf][fv][0];
            }
#if ASYNC_LDS
            __builtin_amdgcn_global_load_lds(
                (const __attribute__((address_space(1))) void*)src,
                (__attribute__((address_space(3))) void*)dst,
                16, 0, 0);
#else
            *(v8bf*)(dst + (size_t)lane * 8) = *(const v8bf*)src;
#endif
        }
    };

    stage(t0, 0);
    __syncthreads();

    for (int t = t0; t < t1; ++t) {
        const int buf = (t - t0) & 1;
        if (t + 1 < t1) stage(t + 1, buf ^ 1);
        const int k0 = t * 64;

        if (k0 <= qw0 + 31) {
            const bool msk = (k0 + 63 > qw0);
            #pragma unroll
            for (int g2 = 0; g2 < 2; ++g2) {
                float s2[4][4];
                #pragma unroll
                for (int t4 = 0; t4 < 4; ++t4) {
                    v4f sa = (v4f)0.0f;
                    #pragma unroll
                    for (int s = 0; s < 3; ++s) {
                        v8bf kb = *(const v8bf*)&Kf[buf][t4 * 3 + s][(size_t)lane * 8];
                        sa = __builtin_amdgcn_mfma_f32_16x16x32_bf16(qa[g2][s], kb, sa, 0, 0, 0);
                    }
                    #pragma unroll
                    for (int r = 0; r < 4; ++r) s2[t4][r] = sa[r];
                }
                if (msk) {
                    #pragma unroll
                    for (int t4 = 0; t4 < 4; ++t4)
                        #pragma unroll
                        for (int r = 0; r < 4; ++r)
                            if (k0 + t4 * 16 + mlow > qw0 + g2 * 16 + kq * 4 + r)
                                s2[t4][r] = -1e20f;
                }

                v4f pvv[4];
                #pragma unroll
                for (int t4 = 0; t4 < 4; ++t4)
                    #pragma unroll
                    for (int r = 0; r < 4; ++r)
                        pvv[t4][r] = exp2f(s2[t4][r]);
                lsum[g2] += (pvv[0] + pvv[1]) + (pvv[2] + pvv[3]);

                #pragma unroll
                for (int t4 = 0; t4 < 4; ++t4)
                    #pragma unroll
                    for (int r = 0; r < 4; ++r)
                        Ps[wave][kq * 4 + r][t4 * 16 + mlow] = (__bf16)pvv[t4][r];

                v8bf pa0 = *(const v8bf*)&Ps[wave][mlow][kq * 8];
                v8bf pa1 = *(const v8bf*)&Ps[wave][mlow][32 + kq * 8];

                #pragma unroll
                for (int jj = 0; jj < 6; ++jj) {
                    v8bf vb0 = *(const v8bf*)&Vf[buf][jj * 2][(size_t)lane * 8];
                    v8bf vb1 = *(const v8bf*)&Vf[buf][jj * 2 + 1][(size_t)lane * 8];
                    O[g2][jj] = __builtin_amdgcn_mfma_f32_16x16x32_bf16(pa0, vb0, O[g2][jj], 0, 0, 0);
                    O[g2][jj] = __builtin_amdgcn_mfma_f32_16x16x32_bf16(pa1, vb1, O[g2][jj], 0, 0, 0);
                }
            }
        }
        __syncthreads();
    }

    #pragma unroll
    for (int off = 1; off < 16; off <<= 1)
        #pragma unroll
        for (int g2 = 0; g2 < 2; ++g2)
            #pragma unroll
            for (int r = 0; r < 4; ++r)
                lsum[g2][r] += __shfl_xor(lsum[g2][r], off);

    if (nch == 1) {
        #pragma unroll
        for (int g2 = 0; g2 < 2; ++g2)
            #pragma unroll
            for (int r = 0; r < 4; ++r) {
                float inv = 1.0f / lsum[g2][r];
                float* orow = out + ((size_t)b * SEQLEN + qw0 + g2 * 16 + kq * 4 + r) * NH;
                #pragma unroll
                for (int jj = 0; jj < 6; ++jj)
                    orow[jj * 16 + mlow] = O[g2][jj][r] * inv;
            }
    } else {
        const int e = (b * 10 + (qt - 6)) * 3 + c0;
        __bf16* Pp = Opart + (size_t)e * 12288;
        #pragma unroll
        for (int g2 = 0; g2 < 2; ++g2)
            #pragma unroll
            for (int r = 0; r < 4; ++r) {
                const int row = wave * 32 + g2 * 16 + kq * 4 + r;
                float inv = 1.0f / lsum[g2][r];
                #pragma unroll
                for (int jj = 0; jj < 6; ++jj)
                    Pp[row * 96 + jj * 16 + mlow] = (__bf16)(O[g2][jj][r] * inv);
                if (mlow == 0) {
                    ml[(size_t)e * 256 + row * 2]     = 0.0f;
                    ml[(size_t)e * 256 + row * 2 + 1] = lsum[g2][r];
                }
            }
    }
}

// ---------------------------------------------------------------------------
// Merge 2..3 partials per (b, qt>=6). (unchanged)
// ---------------------------------------------------------------------------
__global__ __launch_bounds__(256) void attn_combine(
    const __bf16* __restrict__ Opart,
    const float* __restrict__ ml,
    float* __restrict__ out)
{
    __shared__ float wsh[3][128];
    const int b   = blockIdx.x & 15;
    const int qr  = blockIdx.x >> 4;
    const int qt  = 6 + qr;
    const int nch = (qt >= 12) ? 3 : 2;
    const int e0  = (b * 10 + qr) * 3;
    const int tid = threadIdx.x;

    if (tid < 128) {
        float m[3], l[3];
        float M = -INFINITY;
        #pragma unroll
        for (int c = 0; c < 3; ++c) {
            if (c < nch) {
                m[c] = ml[(size_t)(e0 + c) * 256 + tid * 2];
                l[c] = ml[(size_t)(e0 + c) * 256 + tid * 2 + 1];
            } else { m[c] = -INFINITY; l[c] = 0.0f; }
            M = fmaxf(M, m[c]);
        }
        float a[3], s = 0.0f;
        #pragma unroll
        for (int c = 0; c < 3; ++c) { a[c] = exp2f(m[c] - M) * l[c]; s += a[c]; }
        float inv = 1.0f / s;
        #pragma unroll
        for (int c = 0; c < 3; ++c) wsh[c][tid] = a[c] * inv;
    }
    __syncthreads();

    float* op = out + ((size_t)b * SEQLEN + (size_t)qt * 128) * NH;
    #pragma unroll
    for (int it = 0; it < 6; ++it) {
        int idx = it * 256 + tid;
        int row = idx / 12;
        int off = idx * 8;
        float acc[8];
        #pragma unroll
        for (int k = 0; k < 8; ++k) acc[k] = 0.0f;
        #pragma unroll
        for (int c = 0; c < 3; ++c) {
            if (c < nch) {
                v8bf p = *(const v8bf*)(Opart + (size_t)(e0 + c) * 12288 + off);
                float w = wsh[c][row];
                #pragma unroll
                for (int k = 0; k < 8; ++k) acc[k] += w * (float)p[k];
            }
        }
        *(float4*)(op + off)     = make_float4(acc[0], acc[1], acc[2], acc[3]);
        *(float4*)(op + off + 4) = make_float4(acc[4], acc[5], acc[6], acc[7]);
    }
}

// ---------------------------------------------------------------------------
extern "C" void kernel_launch(void* const* d_in, const int* in_sizes, int n_in,
                              void* d_out, int out_size, void* d_ws, size_t ws_size,
                              hipStream_t stream)
{
    (void)in_sizes; (void)n_in; (void)out_size; (void)ws_size;
    const float* x  = (const float*)d_in[0];
    const float* Wq = (const float*)d_in[1];
    const float* Wk = (const float*)d_in[2];
    const float* Wv = (const float*)d_in[3];
    float* out = (float*)d_out;

    __bf16* qk    = (__bf16*)d_ws;                          // 12.58 MB (Q,K)
    __bf16* vt    = qk + (size_t)2 * MROWS * NH;            //  6.29 MB (V^T)
    __bf16* Wp    = vt + (size_t)NH * MROWS;                //  0.44 MB
    __bf16* Opart = Wp + (size_t)3 * 24 * 6 * 512;          // 11.80 MB (bf16)
    float*  ml    = (float*)(Opart + (size_t)480 * 12288);  //  0.49 MB

    pack_w<<<(3 * 24 * 6 * 64 + 255) / 256, 256, 0, stream>>>(Wq, Wk, Wv, Wp);
    qkv_fused<<<MROWS / 64, 256, 0, stream>>>(x, Wp, qk, vt);
    attn_mfma<<<dim3(480), 256, 0, stream>>>(qk, vt, out, Opart, ml);
    attn_combine<<<dim3(160), 256, 0, stream>>>(Opart, ml, out);
}

// Round 14
// 205.333 us; speedup vs baseline: 1.0901x; 1.0069x over previous
//
#include <hip/hip_runtime.h>
#include <math.h>

#define EMB_K   768
#define NH      96
#define SEQLEN  2048
#define NBATCH  16
#define MROWS   (NBATCH * SEQLEN)   // 32768

typedef __bf16 v8bf __attribute__((ext_vector_type(8)));
typedef float  v4f  __attribute__((ext_vector_type(4)));

// score scale folded into Q at qkv epilogue: (1/sqrt(96)) * log2(e)
#define QSCALE (0.10206207261596575f * 1.4426950408889634f)

#if __has_builtin(__builtin_amdgcn_global_load_lds)
#define ASYNC_LDS 1
#else
#define ASYNC_LDS 0
#endif

// ---------------------------------------------------------------------------
// Pack Wq/Wk/Wv (fp32 [768][96]) into bf16 B-fragment order. (unchanged)
// ---------------------------------------------------------------------------
__global__ __launch_bounds__(256) void pack_w(
    const float* __restrict__ Wq,
    const float* __restrict__ Wk,
    const float* __restrict__ Wv,
    __bf16* __restrict__ Wp)
{
    int t = blockIdx.x * 256 + threadIdx.x;
    if (t >= 3 * 24 * 6 * 64) return;
    int l  = t & 63;
    int fj = (t >> 6) % 6;
    int s  = ((t >> 6) / 6) % 24;
    int w  = (t >> 6) / (6 * 24);
    const float* W = (w == 0) ? Wq : ((w == 1) ? Wk : Wv);
    int n     = fj * 16 + (l & 15);
    int kbase = s * 32 + (l >> 4) * 8;
    __bf16 o[8];
    #pragma unroll
    for (int e = 0; e < 8; ++e)
        o[e] = (__bf16)W[(size_t)(kbase + e) * NH + n];
    *(v8bf*)(Wp + (size_t)t * 8) = *(v8bf*)o;
}

__device__ inline v8bf cvt8(const float4& a, const float4& b)
{
    v8bf r;
    r[0] = (__bf16)a.x; r[1] = (__bf16)a.y; r[2] = (__bf16)a.z; r[3] = (__bf16)a.w;
    r[4] = (__bf16)b.x; r[5] = (__bf16)b.y; r[6] = (__bf16)b.z; r[7] = (__bf16)b.w;
    return r;
}

// ---------------------------------------------------------------------------
// Fused QKV — ROUND 14: 32 rows/wave (128-row block, grid 256).
// r13's structure had an 18:18 ds_read_b128:MFMA ratio; at ~12 cyc/b128
// (m134) that's ~1730 cyc/slice/CU of LDS issue — the real ~50 µs floor.
// Each wave now holds 2 A-frags (rows mlow and mlow+16 of its 32), so the
// same 18 B-reads feed 36 MFMAs (1:2), and each barrier interval covers
// 144 MFMAs/block. Named x registers (x0*/x1* even/odd slice, a/b/c/d for
// the two row-groups), 2-slice-deep prefetch surviving barriers; B(s+1)
// staged via VGPR temps + ds_write_b128 (no global_load_lds vmcnt(0) drain).
// No dynamic register-array indexing anywhere (r11/r12 scratch lesson).
// ---------------------------------------------------------------------------
__global__ __launch_bounds__(256, 2) void qkv_fused(
    const float* __restrict__ x,
    const __bf16* __restrict__ Wp,
    __bf16* __restrict__ qk,
    __bf16* __restrict__ vt)
{
    __shared__ __bf16 Bs[2][18][512];   // 36.9 KB, double-buffered B frags
    __shared__ __bf16 VsT[96][136];     // 26.1 KB, V transpose bounce (128+8)

    const int wave = threadIdx.x >> 6;
    const int lane = threadIdx.x & 63;
    const int mlow = lane & 15;
    const int kq   = lane >> 4;
    const int m0   = blockIdx.x * 128;
    const int r0   = m0 + wave * 32;

    const float* xr0 = x + (size_t)(r0 + mlow) * EMB_K + kq * 8;
    const float* xr1 = xr0 + (size_t)16 * EMB_K;

    // frags owned by this wave: f = wave + 4*i  (waves 0,1: 5 frags; 2,3: 4)
    const int nf = (wave < 2) ? 5 : 4;

    v4f accA[3][6], accB[3][6];         // row-groups 0 (rows 0-15), 1 (16-31)
    #pragma unroll
    for (int w = 0; w < 3; ++w)
        #pragma unroll
        for (int j = 0; j < 6; ++j) {
            accA[w][j] = (v4f)0.0f;
            accB[w][j] = (v4f)0.0f;
        }

    // prologue: B(0) -> LDS, x(0), x(1) -> named regs
    v8bf btmp[5];
    #pragma unroll
    for (int i = 0; i < 5; ++i)
        if (i < nf) {
            const int f = wave + 4 * i;
            btmp[i] = *(const v8bf*)(Wp + ((size_t)((f / 6) * 24) * 6 + (f % 6)) * 512
                                        + (size_t)lane * 8);
        }
    float4 x0a = *(const float4*)(xr0);
    float4 x0b = *(const float4*)(xr0 + 4);
    float4 x0c = *(const float4*)(xr1);
    float4 x0d = *(const float4*)(xr1 + 4);
    float4 x1a = *(const float4*)(xr0 + 32);
    float4 x1b = *(const float4*)(xr0 + 36);
    float4 x1c = *(const float4*)(xr1 + 32);
    float4 x1d = *(const float4*)(xr1 + 36);
    #pragma unroll
    for (int i = 0; i < 5; ++i)
        if (i < nf)
            *(v8bf*)&Bs[0][wave + 4 * i][(size_t)lane * 8] = btmp[i];
    __syncthreads();

    for (int sp = 0; sp < 12; ++sp) {
        // ---- even slice s0 = 2*sp: consumes x0*, computes on Bs[0] ----
        {
            const int s0 = 2 * sp;
            v8bf a0 = cvt8(x0a, x0b);
            v8bf a1 = cvt8(x0c, x0d);
            // B(s0+1) loads first (older in vmcnt FIFO)
            #pragma unroll
            for (int i = 0; i < 5; ++i)
                if (i < nf) {
                    const int f = wave + 4 * i;
                    btmp[i] = *(const v8bf*)(Wp + ((size_t)((f / 6) * 24 + (s0 + 1)) * 6
                                                   + (f % 6)) * 512 + (size_t)lane * 8);
                }
            // x(s0+2) second (newer: stays in flight across the B wait)
            if (s0 < 22) {
                x0a = *(const float4*)(xr0 + (s0 + 2) * 32);
                x0b = *(const float4*)(xr0 + (s0 + 2) * 32 + 4);
                x0c = *(const float4*)(xr1 + (s0 + 2) * 32);
                x0d = *(const float4*)(xr1 + (s0 + 2) * 32 + 4);
            }
            #pragma unroll
            for (int w = 0; w < 3; ++w)
                #pragma unroll
                for (int j = 0; j < 6; ++j) {
                    v8bf bf = *(const v8bf*)&Bs[0][w * 6 + j][(size_t)lane * 8];
                    accA[w][j] = __builtin_amdgcn_mfma_f32_16x16x32_bf16(a0, bf, accA[w][j], 0, 0, 0);
                    accB[w][j] = __builtin_amdgcn_mfma_f32_16x16x32_bf16(a1, bf, accB[w][j], 0, 0, 0);
                }
            #pragma unroll
            for (int i = 0; i < 5; ++i)
                if (i < nf)
                    *(v8bf*)&Bs[1][wave + 4 * i][(size_t)lane * 8] = btmp[i];
            __syncthreads();
        }
        // ---- odd slice s1 = 2*sp+1: consumes x1*, computes on Bs[1] ----
        {
            const int s1 = 2 * sp + 1;
            v8bf a0 = cvt8(x1a, x1b);
            v8bf a1 = cvt8(x1c, x1d);
            if (s1 < 23) {
                #pragma unroll
                for (int i = 0; i < 5; ++i)
                    if (i < nf) {
                        const int f = wave + 4 * i;
                        btmp[i] = *(const v8bf*)(Wp + ((size_t)((f / 6) * 24 + (s1 + 1)) * 6
                                                       + (f % 6)) * 512 + (size_t)lane * 8);
                    }
            }
            if (s1 < 22) {
                x1a = *(const float4*)(xr0 + (s1 + 2) * 32);
                x1b = *(const float4*)(xr0 + (s1 + 2) * 32 + 4);
                x1c = *(const float4*)(xr1 + (s1 + 2) * 32);
                x1d = *(const float4*)(xr1 + (s1 + 2) * 32 + 4);
            }
            #pragma unroll
            for (int w = 0; w < 3; ++w)
                #pragma unroll
                for (int j = 0; j < 6; ++j) {
                    v8bf bf = *(const v8bf*)&Bs[1][w * 6 + j][(size_t)lane * 8];
                    accA[w][j] = __builtin_amdgcn_mfma_f32_16x16x32_bf16(a0, bf, accA[w][j], 0, 0, 0);
                    accB[w][j] = __builtin_amdgcn_mfma_f32_16x16x32_bf16(a1, bf, accB[w][j], 0, 0, 0);
                }
            if (s1 < 23) {
                #pragma unroll
                for (int i = 0; i < 5; ++i)
                    if (i < nf)
                        *(v8bf*)&Bs[0][wave + 4 * i][(size_t)lane * 8] = btmp[i];
            }
            __syncthreads();
        }
    }

    // Q, K epilogue (Q pre-scaled by QSCALE), both row-groups
    #pragma unroll
    for (int w = 0; w < 2; ++w) {
        __bf16* op = qk + (size_t)w * MROWS * NH;
        const float sc = (w == 0) ? QSCALE : 1.0f;
        #pragma unroll
        for (int j = 0; j < 6; ++j)
            #pragma unroll
            for (int r = 0; r < 4; ++r) {
                op[(size_t)(r0 + kq * 4 + r) * NH + j * 16 + mlow] =
                    (__bf16)(accA[w][j][r] * sc);
                op[(size_t)(r0 + 16 + kq * 4 + r) * NH + j * 16 + mlow] =
                    (__bf16)(accB[w][j][r] * sc);
            }
    }
    // V -> LDS transposed, then coalesced store to vt[96][32768]
    #pragma unroll
    for (int j = 0; j < 6; ++j)
        #pragma unroll
        for (int r = 0; r < 4; ++r) {
            VsT[j * 16 + mlow][wave * 32 + kq * 4 + r]      = (__bf16)accA[2][j][r];
            VsT[j * 16 + mlow][wave * 32 + 16 + kq * 4 + r] = (__bf16)accB[2][j][r];
        }
    __syncthreads();
    #pragma unroll
    for (int it = 0; it < 6; ++it) {
        int idx = it * 256 + threadIdx.x;   // 0..1535 = 96 cols x 16 chunks
        int c = idx >> 4, g = idx & 15;
        *(v8bf*)(vt + (size_t)c * MROWS + m0 + g * 8) = *(const v8bf*)&VsT[c][g * 8];
    }
}

// ---------------------------------------------------------------------------
// MFMA causal flash attention — block-cooperative K/V staging.
// (byte-identical to round 10 — frozen for attribution)
// ---------------------------------------------------------------------------
__device__ const unsigned char JTAB[30] = {
    20, 24, 28, 32, 36, 40, 44, 45, 48, 49, 52, 53, 56, 57, 60, 61,
    0, 4, 8, 12, 16, 25, 29, 33, 37, 41, 50, 54, 58, 62
};

__global__ __launch_bounds__(256, 2) void attn_mfma(
    const __bf16* __restrict__ qk,
    const __bf16* __restrict__ vt,
    float* __restrict__ out,
    __bf16* __restrict__ Opart,
    float* __restrict__ ml)
{
    __shared__ __bf16 Kf[2][12][512];
    __shared__ __bf16 Vf[2][12][512];
    __shared__ __bf16 Ps[4][16][72];

    const int bid = blockIdx.x;
    const int b   = bid & 15;
    const int j   = bid >> 4;
    const int enc = JTAB[j];
    const int qt  = enc >> 2;
    const int c0  = enc & 3;
    const int ntiles = 2 * qt + 2;
    const int t0  = c0 * 12;
    const int t1  = (t0 + 12 < ntiles) ? (t0 + 12) : ntiles;
    const int nch = (ntiles + 11) / 12;

    const int wave = threadIdx.x >> 6;
    const int lane = threadIdx.x & 63;
    const int mlow = lane & 15;
    const int kq   = lane >> 4;
    const int qw0  = qt * 128 + wave * 32;

    const __bf16* qp  = qk + (size_t)b * SEQLEN * NH;
    const __bf16* kp  = qk + (size_t)MROWS * NH + (size_t)b * SEQLEN * NH;
    const __bf16* vtp = vt + (size_t)b * SEQLEN;

    v8bf qa[2][3];
    #pragma unroll
    for (int g2 = 0; g2 < 2; ++g2)
        #pragma unroll
        for (int s = 0; s < 3; ++s)
            qa[g2][s] = *(const v8bf*)(qp + (size_t)(qw0 + g2 * 16 + mlow) * NH
                                          + s * 32 + kq * 8);

    v4f lsum[2];
    v4f O[2][6];
    #pragma unroll
    for (int g2 = 0; g2 < 2; ++g2) {
        lsum[g2] = (v4f)0.0f;
        #pragma unroll
        for (int jj = 0; jj < 6; ++jj) O[g2][jj] = (v4f)0.0f;
    }

    auto stage = [&](int t, int buf) {
        const int k0 = t * 64;
        #pragma unroll
        for (int i = 0; i < 6; ++i) {
            const int f = wave * 6 + i;
            const __bf16* src;
            __bf16* dst;
            if (f < 12) {
                const int t4 = f / 3, s = f - t4 * 3;
                src = kp + (size_t)(k0 + t4 * 16 + mlow) * NH + s * 32 + kq * 8;
                dst = &Kf[buf][f][0];
            } else {
                const int fv = f - 12;
                const int jj = fv >> 1, h = fv & 1;
                src = vtp + (size_t)(jj * 16 + mlow) * MROWS + k0 + h * 32 + kq * 8;
                dst = &Vf[buf][fv][0];
            }
#if ASYNC_LDS
            __builtin_amdgcn_global_load_lds(
                (const __attribute__((address_space(1))) void*)src,
                (__attribute__((address_space(3))) void*)dst,
                16, 0, 0);
#else
            *(v8bf*)(dst + (size_t)lane * 8) = *(const v8bf*)src;
#endif
        }
    };

    stage(t0, 0);
    __syncthreads();

    for (int t = t0; t < t1; ++t) {
        const int buf = (t - t0) & 1;
        if (t + 1 < t1) stage(t + 1, buf ^ 1);
        const int k0 = t * 64;

        if (k0 <= qw0 + 31) {
            const bool msk = (k0 + 63 > qw0);
            #pragma unroll
            for (int g2 = 0; g2 < 2; ++g2) {
                float s2[4][4];
                #pragma unroll
                for (int t4 = 0; t4 < 4; ++t4) {
                    v4f sa = (v4f)0.0f;
                    #pragma unroll
                    for (int s = 0; s < 3; ++s) {
                        v8bf kb = *(const v8bf*)&Kf[buf][t4 * 3 + s][(size_t)lane * 8];
                        sa = __builtin_amdgcn_mfma_f32_16x16x32_bf16(qa[g2][s], kb, sa, 0, 0, 0);
                    }
                    #pragma unroll
                    for (int r = 0; r < 4; ++r) s2[t4][r] = sa[r];
                }
                if (msk) {
                    #pragma unroll
                    for (int t4 = 0; t4 < 4; ++t4)
                        #pragma unroll
                        for (int r = 0; r < 4; ++r)
                            if (k0 + t4 * 16 + mlow > qw0 + g2 * 16 + kq * 4 + r)
                                s2[t4][r] = -1e20f;
                }

                v4f pvv[4];
                #pragma unroll
                for (int t4 = 0; t4 < 4; ++t4)
                    #pragma unroll
                    for (int r = 0; r < 4; ++r)
                        pvv[t4][r] = exp2f(s2[t4][r]);
                lsum[g2] += (pvv[0] + pvv[1]) + (pvv[2] + pvv[3]);

                #pragma unroll
                for (int t4 = 0; t4 < 4; ++t4)
                    #pragma unroll
                    for (int r = 0; r < 4; ++r)
                        Ps[wave][kq * 4 + r][t4 * 16 + mlow] = (__bf16)pvv[t4][r];

                v8bf pa0 = *(const v8bf*)&Ps[wave][mlow][kq * 8];
                v8bf pa1 = *(const v8bf*)&Ps[wave][mlow][32 + kq * 8];

                #pragma unroll
                for (int jj = 0; jj < 6; ++jj) {
                    v8bf vb0 = *(const v8bf*)&Vf[buf][jj * 2][(size_t)lane * 8];
                    v8bf vb1 = *(const v8bf*)&Vf[buf][jj * 2 + 1][(size_t)lane * 8];
                    O[g2][jj] = __builtin_amdgcn_mfma_f32_16x16x32_bf16(pa0, vb0, O[g2][jj], 0, 0, 0);
                    O[g2][jj] = __builtin_amdgcn_mfma_f32_16x16x32_bf16(pa1, vb1, O[g2][jj], 0, 0, 0);
                }
            }
        }
        __syncthreads();
    }

    #pragma unroll
    for (int off = 1; off < 16; off <<= 1)
        #pragma unroll
        for (int g2 = 0; g2 < 2; ++g2)
            #pragma unroll
            for (int r = 0; r < 4; ++r)
                lsum[g2][r] += __shfl_xor(lsum[g2][r], off);

    if (nch == 1) {
        #pragma unroll
        for (int g2 = 0; g2 < 2; ++g2)
            #pragma unroll
            for (int r = 0; r < 4; ++r) {
                float inv = 1.0f / lsum[g2][r];
                float* orow = out + ((size_t)b * SEQLEN + qw0 + g2 * 16 + kq * 4 + r) * NH;
                #pragma unroll
                for (int jj = 0; jj < 6; ++jj)
                    orow[jj * 16 + mlow] = O[g2][jj][r] * inv;
            }
    } else {
        const int e = (b * 10 + (qt - 6)) * 3 + c0;
        __bf16* Pp = Opart + (size_t)e * 12288;
        #pragma unroll
        for (int g2 = 0; g2 < 2; ++g2)
            #pragma unroll
            for (int r = 0; r < 4; ++r) {
                const int row = wave * 32 + g2 * 16 + kq * 4 + r;
                float inv = 1.0f / lsum[g2][r];
                #pragma unroll
                for (int jj = 0; jj < 6; ++jj)
                    Pp[row * 96 + jj * 16 + mlow] = (__bf16)(O[g2][jj][r] * inv);
                if (mlow == 0) {
                    ml[(size_t)e * 256 + row * 2]     = 0.0f;
                    ml[(size_t)e * 256 + row * 2 + 1] = lsum[g2][r];
                }
            }
    }
}

// ---------------------------------------------------------------------------
// Merge 2..3 partials per (b, qt>=6). (unchanged)
// ---------------------------------------------------------------------------
__global__ __launch_bounds__(256) void attn_combine(
    const __bf16* __restrict__ Opart,
    const float* __restrict__ ml,
    float* __restrict__ out)
{
    __shared__ float wsh[3][128];
    const int b   = blockIdx.x & 15;
    const int qr  = blockIdx.x >> 4;
    const int qt  = 6 + qr;
    const int nch = (qt >= 12) ? 3 : 2;
    const int e0  = (b * 10 + qr) * 3;
    const int tid = threadIdx.x;

    if (tid < 128) {
        float m[3], l[3];
        float M = -INFINITY;
        #pragma unroll
        for (int c = 0; c < 3; ++c) {
            if (c < nch) {
                m[c] = ml[(size_t)(e0 + c) * 256 + tid * 2];
                l[c] = ml[(size_t)(e0 + c) * 256 + tid * 2 + 1];
            } else { m[c] = -INFINITY; l[c] = 0.0f; }
            M = fmaxf(M, m[c]);
        }
        float a[3], s = 0.0f;
        #pragma unroll
        for (int c = 0; c < 3; ++c) { a[c] = exp2f(m[c] - M) * l[c]; s += a[c]; }
        float inv = 1.0f / s;
        #pragma unroll
        for (int c = 0; c < 3; ++c) wsh[c][tid] = a[c] * inv;
    }
    __syncthreads();

    float* op = out + ((size_t)b * SEQLEN + (size_t)qt * 128) * NH;
    #pragma unroll
    for (int it = 0; it < 6; ++it) {
        int idx = it * 256 + tid;
        int row = idx / 12;
        int off = idx * 8;
        float acc[8];
        #pragma unroll
        for (int k = 0; k < 8; ++k) acc[k] = 0.0f;
        #pragma unroll
        for (int c = 0; c < 3; ++c) {
            if (c < nch) {
                v8bf p = *(const v8bf*)(Opart + (size_t)(e0 + c) * 12288 + off);
                float w = wsh[c][row];
                #pragma unroll
                for (int k = 0; k < 8; ++k) acc[k] += w * (float)p[k];
            }
        }
        *(float4*)(op + off)     = make_float4(acc[0], acc[1], acc[2], acc[3]);
        *(float4*)(op + off + 4) = make_float4(acc[4], acc[5], acc[6], acc[7]);
    }
}

// ---------------------------------------------------------------------------
extern "C" void kernel_launch(void* const* d_in, const int* in_sizes, int n_in,
                              void* d_out, int out_size, void* d_ws, size_t ws_size,
                              hipStream_t stream)
{
    (void)in_sizes; (void)n_in; (void)out_size; (void)ws_size;
    const float* x  = (const float*)d_in[0];
    const float* Wq = (const float*)d_in[1];
    const float* Wk = (const float*)d_in[2];
    const float* Wv = (const float*)d_in[3];
    float* out = (float*)d_out;

    __bf16* qk    = (__bf16*)d_ws;                          // 12.58 MB (Q,K)
    __bf16* vt    = qk + (size_t)2 * MROWS * NH;            //  6.29 MB (V^T)
    __bf16* Wp    = vt + (size_t)NH * MROWS;                //  0.44 MB
    __bf16* Opart = Wp + (size_t)3 * 24 * 6 * 512;          // 11.80 MB (bf16)
    float*  ml    = (float*)(Opart + (size_t)480 * 12288);  //  0.49 MB

    pack_w<<<(3 * 24 * 6 * 64 + 255) / 256, 256, 0, stream>>>(Wq, Wk, Wv, Wp);
    qkv_fused<<<MROWS / 128, 256, 0, stream>>>(x, Wp, qk, vt);
    attn_mfma<<<dim3(480), 256, 0, stream>>>(qk, vt, out, Opart, ml);
    attn_combine<<<dim3(160), 256, 0, stream>>>(Opart, ml, out);
}